// Round 8
// baseline (129.908 us; speedup 1.0000x reference)
//
#include <hip/hip_runtime.h>
#include <math.h>

#define NQ 16384
#define MR 16384
#define JTILES (MR / 16)   // 1024
#define CHUNK 8            // j-tiles staged per LDS round (12 KB)

typedef __attribute__((ext_vector_type(8))) short bf16x8;
typedef __attribute__((ext_vector_type(4))) float floatx4;

// round-to-nearest-even fp32 -> bf16 (bit pattern). No NaN/inf in this data.
__device__ __forceinline__ unsigned short bf16_rne(float f) {
    union { float f; unsigned u; } v; v.f = f;
    return (unsigned short)((v.u + 0x7FFFu + ((v.u >> 16) & 1u)) >> 16);
}
__device__ __forceinline__ float bf16_to_f32(unsigned short h) {
    union { unsigned u; float f; } v; v.u = ((unsigned)h) << 16;
    return v.f;
}
// split fp32 v into 3 bf16 terms: v = h + m + l (to ~2^-25 relative)
__device__ __forceinline__ void split3(float v, unsigned short& h,
                                       unsigned short& m, unsigned short& l) {
    h = bf16_rne(v);
    float r1 = v - bf16_to_f32(h);   // exact (Sterbenz)
    m = bf16_rne(r1);
    float r2 = r1 - bf16_to_f32(m);  // exact
    l = bf16_rne(r2);
}

// pack 8 u16 -> one 16B store
__device__ __forceinline__ void store8(unsigned short* p, const unsigned short* s) {
    uint4 a;
    a.x = (unsigned)s[0] | ((unsigned)s[1] << 16);
    a.y = (unsigned)s[2] | ((unsigned)s[3] << 16);
    a.z = (unsigned)s[4] | ((unsigned)s[5] << 16);
    a.w = (unsigned)s[6] | ((unsigned)s[7] << 16);
    *(uint4*)p = a;
}

// VGPR-form MFMA pair-chain (gfx950 unified file). R7 failed because inline
// asm is opaque to the compiler's MFMA hazard recognizer; this version fences
// the hazards explicitly:
//   s_nop 1            -- VALU write -> MFMA operand read (2 wait states)
//   6x v_mfma (q0/q1 interleaved, per-q order f1,f2,f3 = builtin acc order)
//   s_nop 7; s_nop 7   -- MFMA write -> VALU read (16 wait states, covers max)
// MFMA->MFMA same-acc accumulate chains need no waits (standard GEMM idiom).
// Tied "+v" keeps C/D in arch VGPRs: no AGPR shadow, no v_accvgpr_* traffic.
// Bit-identical arithmetic to the builtin sequence.
__device__ __forceinline__ void mfma_chain2(floatx4& acc0, floatx4& acc1,
                                            bf16x8 a10, bf16x8 a11,
                                            bf16x8 a30, bf16x8 a31,
                                            bf16x8 f1, bf16x8 f2, bf16x8 f3) {
    asm("s_nop 1\n\t"
        "v_mfma_f32_16x16x32_bf16 %0, %2, %6, %0\n\t"
        "v_mfma_f32_16x16x32_bf16 %1, %3, %6, %1\n\t"
        "v_mfma_f32_16x16x32_bf16 %0, %2, %7, %0\n\t"
        "v_mfma_f32_16x16x32_bf16 %1, %3, %7, %1\n\t"
        "v_mfma_f32_16x16x32_bf16 %0, %4, %8, %0\n\t"
        "v_mfma_f32_16x16x32_bf16 %1, %5, %8, %1\n\t"
        "s_nop 7\n\t"
        "s_nop 7"
        : "+v"(acc0), "+v"(acc1)
        : "v"(a10), "v"(a11), "v"(a30), "v"(a31),
          "v"(f1), "v"(f2), "v"(f3));
}

// Prep refs: split xb into 3 bf16 planes, B-fragment tile order SWIZZLED:
// element (col=j&15, k) of tile j>>4 lives at tile*256 + (k>>3)*128 + col*8 + (k&7).
// Unchanged from the passing kernel (numerics + layout identical).
__global__ __launch_bounds__(256) void prep_b(const float* __restrict__ xb,
                                              unsigned short* __restrict__ BH,
                                              unsigned short* __restrict__ BM,
                                              unsigned short* __restrict__ BL,
                                              float* __restrict__ xb2) {
    int j = blockIdx.x * 256 + threadIdx.x;
    const float4* r4 = (const float4*)xb + (size_t)j * 4;
    float4 v0 = r4[0], v1 = r4[1], v2 = r4[2], v3 = r4[3];
    float vals[16] = {v0.x, v0.y, v0.z, v0.w, v1.x, v1.y, v1.z, v1.w,
                      v2.x, v2.y, v2.z, v2.w, v3.x, v3.y, v3.z, v3.w};
    float s0 = v0.x * v0.x + v0.y * v0.y + v0.z * v0.z + v0.w * v0.w;
    float s1 = v1.x * v1.x + v1.y * v1.y + v1.z * v1.z + v1.w * v1.w;
    float s2 = v2.x * v2.x + v2.y * v2.y + v2.z * v2.z + v2.w * v2.w;
    float s3 = v3.x * v3.x + v3.y * v3.y + v3.z * v3.z + v3.w * v3.w;
    xb2[j] = (s0 + s1) + (s2 + s3);
    unsigned short h[16], m[16], l[16];
#pragma unroll
    for (int k = 0; k < 16; ++k) split3(vals[k], h[k], m[k], l[k]);
    size_t tb = (size_t)(j >> 4) * 256 + (size_t)(j & 15) * 8;
    store8(BH + tb, h);       store8(BH + tb + 128, h + 8);
    store8(BM + tb, m);       store8(BM + tb + 128, m + 8);
    store8(BL + tb, l);       store8(BL + tb + 128, l + 8);
}

// Main: per wave 2 query-tiles (32 queries); block = 4 waves = 8 q-tiles (128 q).
// R0-R6 model: dur set by VALU issue; builtin MFMA kept C/D in AGPRs ->
// hidden v_accvgpr_read/write VALU traffic + an AGPR shadow invisible in
// VGPR_Count that pinned residency at ~3.6 waves/SIMD (R5==R6 under different
// bounds). This round: VGPR-form MFMA via hazard-fenced inline asm (single
// variable vs R5; R7's fence-less attempt raced and failed correctness).
//   MFMA1: A=[xh|xm] B=[bh|bh]   MFMA2: A=[xh|xm] B=[bm|bm]
//   MFMA3: A=[xh|xl] B=[bl|bh]   (x planes carry the -2), acc init = xb2[col]
// Strict < keeps lowest j on ties.
__global__ __launch_bounds__(256, 5) void nn_mfma(const float* __restrict__ x,
                                                  const unsigned short* __restrict__ BH,
                                                  const unsigned short* __restrict__ BM,
                                                  const unsigned short* __restrict__ BL,
                                                  const float* __restrict__ xb2,
                                                  float* __restrict__ pval,
                                                  int* __restrict__ pidx,
                                                  int msplit) {
    __shared__ unsigned short sB[3][CHUNK * 256];   // 12 KB

    int tid = threadIdx.x;
    int lane = tid & 63;
    int wave = tid >> 6;
    int qt0 = blockIdx.x * 8 + wave * 2;            // 2 q-tiles per wave
    int split = blockIdx.y;
    int JT = JTILES / msplit;                       // tiles in this split
    int t0 = split * JT;

    int n = lane & 15;                              // row (A) / col (B)
    int quad = lane >> 4;
    int halfk = quad & 1;                           // dim half 0..7 / 8..15
    bool low32 = lane < 32;                         // K slot 0..15 vs 16..31
    int eoff2 = halfk * 128 + n * 8;                // shorts, swizzled layout

    // A fragments in-register from raw x (same construction as before)
    bf16x8 A1[2], A3[2];
#pragma unroll
    for (int q = 0; q < 2; ++q) {
        const float* xr = x + ((size_t)(qt0 + q) * 16 + n) * 16 + halfk * 8;
        float4 u0 = ((const float4*)xr)[0];
        float4 u1 = ((const float4*)xr)[1];
        float e[8] = {u0.x, u0.y, u0.z, u0.w, u1.x, u1.y, u1.z, u1.w};
#pragma unroll
        for (int k = 0; k < 8; ++k) {
            unsigned short h, m, l;
            split3(-2.0f * e[k], h, m, l);
            A1[q][k] = (short)(low32 ? h : m);
            A3[q][k] = (short)(low32 ? h : l);
        }
    }

    const unsigned short* f1b = &sB[0][0];
    const unsigned short* f2b = &sB[1][0];
    const unsigned short* f3b = low32 ? &sB[2][0] : &sB[0][0];
    const float* pxv = xb2 + t0 * 16 + n;

    float best[2][4];
    int bjt[2][4];
#pragma unroll
    for (int q = 0; q < 2; ++q)
#pragma unroll
        for (int r = 0; r < 4; ++r) { best[q][r] = INFINITY; bjt[q][r] = t0; }

    for (int c = 0; c < JT; c += CHUNK) {
        __syncthreads();   // previous round's reads complete
        // stage CHUNK tiles x 3 planes: 256 threads x 16B per plane
        {
            size_t gb = (size_t)(t0 + c) * 256 + (size_t)tid * 8;
            uint4 hV = *(const uint4*)(BH + gb);
            uint4 mV = *(const uint4*)(BM + gb);
            uint4 lV = *(const uint4*)(BL + gb);
            ((uint4*)&sB[0][0])[tid] = hV;
            ((uint4*)&sB[1][0])[tid] = mV;
            ((uint4*)&sB[2][0])[tid] = lV;
        }
        __syncthreads();

#pragma unroll
        for (int tt = 0; tt < CHUNK; ++tt) {
            int tg = t0 + c + tt;                   // global j-tile
            bf16x8 f1 = *(const bf16x8*)(f1b + tt * 256 + eoff2);
            bf16x8 f2 = *(const bf16x8*)(f2b + tt * 256 + eoff2);
            bf16x8 f3 = *(const bf16x8*)(f3b + tt * 256 + eoff2);
            float xv = pxv[(c + tt) * 16];
            floatx4 acc0 = {xv, xv, xv, xv};
            floatx4 acc1 = {xv, xv, xv, xv};
            mfma_chain2(acc0, acc1, A1[0], A1[1], A3[0], A3[1], f1, f2, f3);
#pragma unroll
            for (int r = 0; r < 4; ++r) {
                float s0 = acc0[r];
                if (s0 < best[0][r]) { best[0][r] = s0; bjt[0][r] = tg; }
                float s1 = acc1[r];
                if (s1 < best[1][r]) { best[1][r] = s1; bjt[1][r] = tg; }
            }
        }
    }

    // Cross-lane argmin per row (row = quad*4 + r); lex (value, j).
#pragma unroll
    for (int q = 0; q < 2; ++q) {
#pragma unroll
        for (int r = 0; r < 4; ++r) {
            float v = best[q][r];
            int j = bjt[q][r] * 16 + n;
#pragma unroll
            for (int d = 1; d < 16; d <<= 1) {
                float ov = __shfl_xor(v, d, 64);
                int oj = __shfl_xor(j, d, 64);
                if (ov < v || (ov == v && oj < j)) { v = ov; j = oj; }
            }
            if (n == 0) {
                int gq = (qt0 + q) * 16 + quad * 4 + r;
                pval[(size_t)split * NQ + gq] = v;
                pidx[(size_t)split * NQ + gq] = j;
            }
        }
    }
}

// Combine splits (ascending => lowest j wins ties via strict <), gather y.
__global__ __launch_bounds__(256) void nn_combine(const float* __restrict__ pval,
                                                  const int* __restrict__ pidx,
                                                  const float* __restrict__ y,
                                                  float* __restrict__ out,
                                                  int msplit) {
    int q = blockIdx.x * 256 + threadIdx.x;
    if (q >= NQ) return;
    float bv = INFINITY;
    int bj = 0;
    for (int s = 0; s < msplit; ++s) {
        float v = pval[(size_t)s * NQ + q];
        int id = pidx[(size_t)s * NQ + q];
        if (v < bv) { bv = v; bj = id; }
    }
    out[q] = y[bj];
}

extern "C" void kernel_launch(void* const* d_in, const int* in_sizes, int n_in,
                              void* d_out, int out_size, void* d_ws, size_t ws_size,
                              hipStream_t stream) {
    const float* x  = (const float*)d_in[0];   // [NQ, 16]
    const float* xb = (const float*)d_in[1];   // [MR, 16]
    const float* y  = (const float*)d_in[2];   // [MR]
    float* out = (float*)d_out;                // [NQ]

    // ws need: 3*MR*16*2 (planes) + MR*4 (xb2) + msplit*NQ*8 = 3.58MB @ msplit=16
    int msplit = 16;
    while (msplit > 1 &&
           (size_t)3 * MR * 16 * 2 + (size_t)MR * 4 + (size_t)msplit * NQ * 8 > ws_size) {
        msplit >>= 1;
    }

    unsigned short* BH = (unsigned short*)d_ws;
    unsigned short* BM = BH + (size_t)MR * 16;
    unsigned short* BL = BM + (size_t)MR * 16;
    float* xb2  = (float*)(BL + (size_t)MR * 16);
    float* pval = xb2 + MR;
    int*   pidx = (int*)(pval + (size_t)msplit * NQ);

    prep_b<<<MR / 256, 256, 0, stream>>>(xb, BH, BM, BL, xb2);
    dim3 grid(NQ / 128, msplit);               // 128 x 16 = 2048 blocks
    nn_mfma<<<grid, 256, 0, stream>>>(x, BH, BM, BL, xb2, pval, pidx, msplit);
    nn_combine<<<NQ / 256, 256, 0, stream>>>(pval, pidx, y, out, msplit);
}